// Round 12
// baseline (357.394 us; speedup 1.0000x reference)
//
#include <hip/hip_runtime.h>
#include <cstdint>
#include <cstddef>

#define EPSF 1e-5f
#define BKT 256
#define BKT_SHIFT 8
#define SC_E 4096

typedef unsigned long long ull;
typedef __attribute__((ext_vector_type(8))) short bf16x8;
typedef __attribute__((ext_vector_type(4))) float f32x4;

// ================================================================= CSR build
// Bucket = BKT consecutive destination nodes. NB = ceil(N/BKT) <= 512.
// meta = (colLow << 17) | row  (N <= 131072).
// sedge payload = {row, w}: dinv factored out (applied in GEMM epilogue for
// sources, gather epilogue for dests) -> build needs NO cross-bucket dinv.

__global__ __launch_bounds__(512) void bucket_hist(const int* __restrict__ col,
                                                   int* __restrict__ bhist, int E, int NB) {
    __shared__ int lh[512];
    const int t = threadIdx.x;
    lh[t] = 0;
    __syncthreads();
    for (int e = blockIdx.x * 512 + t; e < E; e += gridDim.x * 512)
        atomicAdd(&lh[col[e] >> BKT_SHIFT], 1);
    __syncthreads();
    if (t < NB && lh[t]) atomicAdd(&bhist[t], lh[t]);
}

__global__ __launch_bounds__(512) void scan_buckets(const int* __restrict__ bhist,
                                                    int* __restrict__ bstart,
                                                    int* __restrict__ bcursor,
                                                    int* __restrict__ rs,
                                                    int NB, int N, int E) {
    __shared__ int part[512];
    const int t = threadIdx.x;
    part[t] = (t < NB) ? bhist[t] : 0;
    __syncthreads();
    for (int off = 1; off < 512; off <<= 1) {
        int v = (t >= off) ? part[t - off] : 0;
        __syncthreads();
        part[t] += v;
        __syncthreads();
    }
    int excl = (t == 0) ? 0 : part[t - 1];
    if (t < NB) { bstart[t] = excl; bcursor[t] = excl; }
    if (t == 0) { bstart[NB] = E; rs[N] = E; }
}

// multisplit scatter: LDS-sort a 4096-edge chunk by bucket, write runs contiguously
__global__ __launch_bounds__(512) void bucket_scatter(const int* __restrict__ row,
                                                      const int* __restrict__ col,
                                                      const float* __restrict__ w,
                                                      int* __restrict__ bcursor,
                                                      int2* __restrict__ brecs,
                                                      int E, int NB) {
    __shared__ int lh[512], lstart[512], lcur[512], gbase[512];
    __shared__ int   sm[SC_E];
    __shared__ float sw[SC_E];
    __shared__ short sb[SC_E];

    const int t = threadIdx.x;
    const int base = blockIdx.x * SC_E;
    const int cnt = min(SC_E, E - base);

    lh[t] = 0;
    __syncthreads();

    int   myb[8], mym[8];
    float myw[8];
#pragma unroll
    for (int k = 0; k < 8; ++k) {
        int i = t + k * 512;
        if (i < cnt) {
            int e = base + i;
            int r = row[e], c = col[e];
            myb[k] = c >> BKT_SHIFT;
            mym[k] = ((c & (BKT - 1)) << 17) | r;
            myw[k] = w[e];
            atomicAdd(&lh[myb[k]], 1);
        } else myb[k] = -1;
    }
    __syncthreads();

    int v = lh[t];
    lstart[t] = v;
    __syncthreads();
    for (int off = 1; off < 512; off <<= 1) {
        int u = (t >= off) ? lstart[t - off] : 0;
        __syncthreads();
        lstart[t] += u;
        __syncthreads();
    }
    int excl = lstart[t] - v;
    __syncthreads();
    lstart[t] = excl;
    lcur[t]   = excl;
    gbase[t]  = (t < NB) ? atomicAdd(&bcursor[t], v) : 0;
    __syncthreads();

#pragma unroll
    for (int k = 0; k < 8; ++k) {
        if (myb[k] >= 0) {
            int slot = atomicAdd(&lcur[myb[k]], 1);
            sm[slot] = mym[k];
            sw[slot] = myw[k];
            sb[slot] = (short)myb[k];
        }
    }
    __syncthreads();

    for (int j = t; j < cnt; j += 512) {
        int b = sb[j];
        int pos = gbase[b] + (j - lstart[b]);
        brecs[pos] = make_int2(sm[j], __float_as_int(sw[j]));
    }
}

// merged build: phase 1 = per-node counts + weighted degree (LDS atomics) ->
// rs, dinv; phase 2 = node-sorted placement of {row, w} (brecs re-read is
// L2-hot; no dinv needed since norm is factored out).
__global__ __launch_bounds__(256) void bucket_build(const int2* __restrict__ brecs,
                                                    const int* __restrict__ bstart,
                                                    int* __restrict__ rs,
                                                    float* __restrict__ dinv,
                                                    int2* __restrict__ sedge, int N) {
    __shared__ int   lcnt[256], lscan[256], lcur[256];
    __shared__ float ldeg[256];
    const int b = blockIdx.x, t = threadIdx.x;
    const int s = bstart[b], e = bstart[b + 1];
    const int node0 = b << BKT_SHIFT;
    const int nNodes = min(BKT, N - node0);

    lcnt[t] = 0;
    ldeg[t] = 0.f;
    __syncthreads();

    for (int i = s + t; i < e; i += 256) {
        int2 r = brecs[i];
        int cl = r.x >> 17;
        atomicAdd(&lcnt[cl], 1);
        atomicAdd(&ldeg[cl], __int_as_float(r.y));
    }
    __syncthreads();

    int v = lcnt[t];
    lscan[t] = v;
    __syncthreads();
    for (int off = 1; off < 256; off <<= 1) {
        int u = (t >= off) ? lscan[t - off] : 0;
        __syncthreads();
        lscan[t] += u;
        __syncthreads();
    }
    int excl = lscan[t] - v;
    lcur[t] = s + excl;
    if (t < nNodes) {
        rs[node0 + t] = s + excl;
        float d = ldeg[t];
        dinv[node0 + t] = (d > 0.f) ? rsqrtf(d) : 0.f;
    }
    __syncthreads();

    for (int i = s + t; i < e; i += 256) {
        int2 r = brecs[i];
        int slot = atomicAdd(&lcur[r.x >> 17], 1);
        sedge[slot] = make_int2(r.x & 0x1FFFF, r.y);   // {row, w}
    }
}

// ================================================================= GEMM (bf16 MFMA)
__device__ __forceinline__ ushort f2bf(float f) {
    uint b = __float_as_uint(f);
    return (ushort)((b + 0x7FFFu + ((b >> 16) & 1u)) >> 16);  // RNE
}
__device__ __forceinline__ float bf2f(ushort u) {
    return __uint_as_float((uint)u << 16);
}
__device__ __forceinline__ uint4 pack8(const float* f) {
    uint4 o;
    o.x = f2bf(f[0]) | ((uint)f2bf(f[1]) << 16);
    o.y = f2bf(f[2]) | ((uint)f2bf(f[3]) << 16);
    o.z = f2bf(f[4]) | ((uint)f2bf(f[5]) << 16);
    o.w = f2bf(f[6]) | ((uint)f2bf(f[7]) << 16);
    return o;
}

// Persistent-W + dinv-scaled epilogue: Y[n] = dinv[n] * (X[n] @ W^T)  (bf16).
// MODE 0: X = f32, plain. MODE 2: X = bf16, BN+ReLU applied during A-staging.
template <int MODE>
__global__ __launch_bounds__(256) void gemm128_mfma(const void* __restrict__ Xv,
                                                    const float* __restrict__ W,
                                                    ushort* __restrict__ Y, int N,
                                                    const float* __restrict__ sums,
                                                    float invN,
                                                    const float* __restrict__ dinv) {
    __shared__ __align__(16) ushort Alds[64][128];
    __shared__ __align__(16) ushort Blds[128][128];
    __shared__ float bnmu[128], bnrs[128];

    const int t = threadIdx.x;

    if constexpr (MODE == 2) {
        if (t < 128) {
            float mu  = sums[t] * invN;
            float var = sums[128 + t] * invN - mu * mu;
            bnmu[t] = mu;
            bnrs[t] = rsqrtf(var + EPSF);
        }
    }

    for (int i = t; i < 128 * 16; i += 256) {
        int j = i >> 4, kc = (i & 15) << 3;
        float f[8];
        *(float4*)&f[0] = *(const float4*)&W[j * 128 + kc];
        *(float4*)&f[4] = *(const float4*)&W[j * 128 + kc + 4];
        *(uint4*)&Blds[j][kc ^ ((j & 7) << 3)] = pack8(f);
    }

    const int lane  = t & 63;
    const int wv    = t >> 6;
    const int arow  = wv * 16 + (lane & 15);
    const int klane = (lane >> 4) << 3;
    const int cq    = lane & 15;
    const int nTiles = (N + 63) >> 6;

    for (int tile = blockIdx.x; tile < nTiles; tile += gridDim.x) {
        const int n0 = tile * 64;
        __syncthreads();  // W/bnmu visible (1st iter); prior MFMA reads done (later)

        for (int i = t; i < 64 * 16; i += 256) {
            int r = i >> 4, kc = (i & 15) << 3;
            int n = n0 + r;
            uint4 v = make_uint4(0u, 0u, 0u, 0u);
            if (n < N) {
                if constexpr (MODE == 0) {
                    float f[8];
                    *(float4*)&f[0] = *(const float4*)&((const float*)Xv)[(size_t)n * 128 + kc];
                    *(float4*)&f[4] = *(const float4*)&((const float*)Xv)[(size_t)n * 128 + kc + 4];
                    v = pack8(f);
                } else {
                    uint4 raw = *(const uint4*)&((const ushort*)Xv)[(size_t)n * 128 + kc];
                    const uint* rw = &raw.x;
                    float f[8];
#pragma unroll
                    for (int k = 0; k < 4; ++k) {
                        float lo = __uint_as_float(rw[k] << 16);
                        float hi = __uint_as_float(rw[k] & 0xFFFF0000u);
                        f[2 * k]     = fmaxf((lo - bnmu[kc + 2 * k])     * bnrs[kc + 2 * k],     0.f);
                        f[2 * k + 1] = fmaxf((hi - bnmu[kc + 2 * k + 1]) * bnrs[kc + 2 * k + 1], 0.f);
                    }
                    v = pack8(f);
                }
            }
            *(uint4*)&Alds[r][kc ^ ((r & 7) << 3)] = v;
        }
        __syncthreads();

        f32x4 acc[8] = {};
        for (int ks = 0; ks < 4; ++ks) {
            const int k0 = ks * 32 + klane;
            bf16x8 a = *(const bf16x8*)&Alds[arow][k0 ^ ((arow & 7) << 3)];
#pragma unroll
            for (int tl = 0; tl < 8; ++tl) {
                int colr = tl * 16 + cq;
                bf16x8 bb = *(const bf16x8*)&Blds[colr][k0 ^ ((colr & 7) << 3)];
                acc[tl] = __builtin_amdgcn_mfma_f32_16x16x32_bf16(a, bb, acc[tl], 0, 0, 0);
            }
        }

        const int r0 = n0 + wv * 16 + ((lane >> 4) << 2);
        float dv[4];
#pragma unroll
        for (int reg = 0; reg < 4; ++reg)
            dv[reg] = (r0 + reg < N) ? dinv[r0 + reg] : 0.f;
#pragma unroll
        for (int tl = 0; tl < 8; ++tl) {
#pragma unroll
            for (int reg = 0; reg < 4; ++reg) {
                int rr = r0 + reg;
                if (rr < N) Y[(size_t)rr * 128 + tl * 16 + cq] = f2bf(acc[tl][reg] * dv[reg]);
            }
        }
    }
}

// ================================================================= gather conv
// Feature-split XCD gather: block's XCD (blockIdx%8, HW round-robin) selects
// feature half -> per-XCD L2 working set halves (25.6 -> 12.8 MB).
// One wave per dest node (half features). Quarter g handles edge j+g; lane lq
// loads uint2 = 4 bf16 features of the half-row -> one vmem op = 4 half-rows.
// sedge = {row, w}; epilogue: out = acc * dinv[c] (+ bias AFTER scaling).
// All __shfl unconditional with in-range sources (round-9 lesson).
__device__ __forceinline__ float bflo(uint v) { return __uint_as_float(v << 16); }
__device__ __forceinline__ float bfhi(uint v) { return __uint_as_float(v & 0xFFFF0000u); }

template <bool OUT_BF16>
__global__ __launch_bounds__(256) void agg_gather(const ushort* __restrict__ Hin,
                                                  const int2* __restrict__ sedge,
                                                  const int* __restrict__ rs,
                                                  const float* __restrict__ dinv,
                                                  const float* __restrict__ bias,
                                                  void* __restrict__ Hout,
                                                  int N, int E, int G) {
    const int bid  = blockIdx.x;
    const int xcd  = bid & 7;
    const int half = xcd >> 2;                      // XCDs 0-3: feats 0-63; 4-7: 64-127
    const int ng   = (bid >> 3) * 4 + (xcd & 3);    // node-group index
    if (ng >= G) return;
    const int c = ng * 4 + (threadIdx.x >> 6);
    if (c >= N) return;

    const int lane = threadIdx.x & 63;
    const int g  = lane >> 4;   // quarter id = edge offset
    const int lq = lane & 15;   // 4 features per lane
    const int fb = half * 64 + lq * 4;

    float acc[4] = {0.f, 0.f, 0.f, 0.f};

    const int e0 = rs[c];
    const int deg = rs[c + 1] - e0;

    for (int base = 0; base < deg; base += 64) {
        int m = min(64, deg - base);
        int idx = e0 + base + lane;
        int2 rec = sedge[idx < E ? idx : E - 1];

        int j = 0;
#define QLOAD(p, rr, ww, vv)                                                    \
        int   rr = __shfl(rec.x, j + 4 * (p) + g);                              \
        float ww = __int_as_float(__shfl(rec.y, j + 4 * (p) + g));              \
        uint2 vv = *(const uint2*)&Hin[(size_t)rr * 128 + fb];
#define QACC(ww, vv)                                                            \
        acc[0] = fmaf(ww, bflo(vv.x), acc[0]); acc[1] = fmaf(ww, bfhi(vv.x), acc[1]); \
        acc[2] = fmaf(ww, bflo(vv.y), acc[2]); acc[3] = fmaf(ww, bfhi(vv.y), acc[3]);

        for (; j + 15 < m; j += 16) {
            QLOAD(0, r0, w0, v0) QLOAD(1, r1, w1, v1)
            QLOAD(2, r2, w2, v2) QLOAD(3, r3, w3, v3)
            QACC(w0, v0) QACC(w1, v1) QACC(w2, v2) QACC(w3, v3)
        }
        for (; j < m; j += 4) {
            int jj = j + g;
            int sl = (jj < m) ? jj : j;       // always < m: source lane active
            int   r0 = __shfl(rec.x, sl);     // unconditional shfl, full exec
            float w0 = __int_as_float(__shfl(rec.y, sl));
            if (jj >= m) w0 = 0.f;            // mask AFTER the cross-lane op
            uint2 v0 = *(const uint2*)&Hin[(size_t)r0 * 128 + fb];
            QACC(w0, v0)
        }
#undef QLOAD
#undef QACC
    }

#pragma unroll
    for (int k = 0; k < 4; ++k) {
        acc[k] += __shfl_xor(acc[k], 16);
        acc[k] += __shfl_xor(acc[k], 32);
    }

    if (g == 0) {
        const float dc = dinv[c];
        float val[4];
#pragma unroll
        for (int k = 0; k < 4; ++k) val[k] = acc[k] * dc;
        if (bias) {
            float4 bv = *(const float4*)&bias[fb];
            val[0] += bv.x; val[1] += bv.y; val[2] += bv.z; val[3] += bv.w;
        }
        if constexpr (OUT_BF16) {
            uint2 o;
            o.x = f2bf(val[0]) | ((uint)f2bf(val[1]) << 16);
            o.y = f2bf(val[2]) | ((uint)f2bf(val[3]) << 16);
            *(uint2*)&((uint*)Hout)[(size_t)c * 64 + half * 32 + lq * 2] = o;
        } else {
            *(float4*)&((float*)Hout)[(size_t)c * 128 + fb] = *(float4*)val;
        }
    }
}

// ================================================================= batchnorm stats (bf16 in)
__global__ __launch_bounds__(256) void bn_stats(const ushort* __restrict__ H,
                                                float* __restrict__ sums, int N) {
    int j = threadIdx.x & 127;
    float s = 0.f, s2 = 0.f;
    for (int n = blockIdx.x * 2 + (threadIdx.x >> 7); n < N; n += gridDim.x * 2) {
        float v = bf2f(H[(size_t)n * 128 + j]);
        s += v; s2 += v * v;
    }
    atomicAdd(&sums[j], s);
    atomicAdd(&sums[128 + j], s2);
}

// ================================================================= launch
extern "C" void kernel_launch(void* const* d_in, const int* in_sizes, int n_in,
                              void* d_out, int out_size, void* d_ws, size_t ws_size,
                              hipStream_t stream) {
    const float* x  = (const float*)d_in[0];
    const int*   ei = (const int*)d_in[1];
    const float* ew = (const float*)d_in[2];
    const float* W0 = (const float*)d_in[3];
    const float* W1 = (const float*)d_in[5];
    const float* b1 = (const float*)d_in[6];

    const int N = in_sizes[0] / 128;
    const int E = in_sizes[2];
    const int* row = ei;
    const int* col = ei + E;
    const int NB = (N + BKT - 1) >> BKT_SHIFT;  // 391 for N=100K (<=512 required)

    uintptr_t base = (uintptr_t)d_ws;
    auto alloc = [&](size_t bytes) {
        uintptr_t p = base;
        base += (bytes + 255) & ~(size_t)255;
        return (void*)p;
    };
    float*  dinv   = (float*) alloc((size_t)N * 4);
    float*  sums   = (float*) alloc(256 * 4);
    int*    bhist  = (int*)   alloc((size_t)(NB + 1) * 4);
    int*    bstart = (int*)   alloc((size_t)(NB + 1) * 4);
    int*    bcursor= (int*)   alloc((size_t)NB * 4);
    int*    rs     = (int*)   alloc((size_t)(N + 1) * 4);
    int2*   sedge  = (int2*)  alloc((size_t)E * 8);        // final {row, w}
    ushort* hA     = (ushort*)alloc((size_t)N * 128 * 2);  // bf16 feature buffers
    ushort* hB     = (ushort*)alloc((size_t)N * 128 * 2);
    // brecs (bucket-partitioned temps) aliases hB: hB first written by conv1,
    // long after bucket_build consumed brecs.
    int2*   brecs  = (int2*)hB;
    float*  out    = (float*) d_out;
    (void)ws_size; (void)n_in; (void)out_size;

    const float invN = 1.f / (float)N;

    // per-call zeroing (harness does not re-poison between replays)
    hipMemsetAsync(bhist, 0, (size_t)(NB + 1) * 4, stream);
    hipMemsetAsync(sums, 0, 256 * 4, stream);

    // --- CSR build: hist -> scan -> multisplit scatter -> merged build
    bucket_hist<<<1024, 512, 0, stream>>>(col, bhist, E, NB);
    scan_buckets<<<1, 512, 0, stream>>>(bhist, bstart, bcursor, rs, NB, N, E);
    bucket_scatter<<<(E + SC_E - 1) / SC_E, 512, 0, stream>>>(row, col, ew, bcursor,
                                                              brecs, E, NB);
    bucket_build<<<NB, 256, 0, stream>>>(brecs, bstart, rs, dinv, sedge, N);

    const int nTiles = (N + 63) / 64;
    const int gemmGrid = nTiles < 512 ? nTiles : 512;
    const int G = (N + 3) / 4;                 // node groups (4 nodes/group)
    const int convGrid = 8 * ((G + 3) / 4);    // x2 feature halves, XCD-mapped

    // --- layer 0: hA(bf16) = dinv * (x @ W0^T)
    gemm128_mfma<0><<<gemmGrid, 256, 0, stream>>>(x, W0, hA, N, nullptr, 0.f, dinv);

    // --- conv 1: hB(bf16) = dinv[c] * gather(hA)
    agg_gather<true><<<convGrid, 256, 0, stream>>>(hA, sedge, rs, dinv, nullptr,
                                                   hB, N, E, G);

    // --- BN stats on bf16 conv output (b0 cancels inside BN)
    bn_stats<<<512, 256, 0, stream>>>(hB, sums, N);

    // --- layer 1 (BN+ReLU fused into A-staging): hA = dinv * (relu(BN(hB)) @ W1^T)
    gemm128_mfma<2><<<gemmGrid, 256, 0, stream>>>(hB, W1, hA, N, sums, invN, dinv);

    // --- conv 2: out(f32) = dinv[c] * gather(hA) + b1
    agg_gather<false><<<convGrid, 256, 0, stream>>>(hA, sedge, rs, dinv, b1,
                                                    out, N, E, G);
}

// Round 14
// 291.716 us; speedup vs baseline: 1.2251x; 1.2251x over previous
//
#include <hip/hip_runtime.h>
#include <cstdint>
#include <cstddef>

#define EPSF 1e-5f
#define BKT 256
#define BKT_SHIFT 8
#define SC_E 4096

typedef unsigned long long ull;
typedef __attribute__((ext_vector_type(8))) short bf16x8;
typedef __attribute__((ext_vector_type(4))) float f32x4;

// ================================================================= CSR build
// Bucket = BKT consecutive destination nodes. NB = ceil(N/BKT) <= 512.
// meta = (colLow << 17) | row  (N <= 131072).

__global__ __launch_bounds__(512) void bucket_hist(const int* __restrict__ col,
                                                   int* __restrict__ bhist, int E, int NB) {
    __shared__ int lh[512];
    const int t = threadIdx.x;
    lh[t] = 0;
    __syncthreads();
    for (int e = blockIdx.x * 512 + t; e < E; e += gridDim.x * 512)
        atomicAdd(&lh[col[e] >> BKT_SHIFT], 1);
    __syncthreads();
    if (t < NB && lh[t]) atomicAdd(&bhist[t], lh[t]);
}

__global__ __launch_bounds__(512) void scan_buckets(const int* __restrict__ bhist,
                                                    int* __restrict__ bstart,
                                                    int* __restrict__ bcursor,
                                                    int* __restrict__ rs,
                                                    int NB, int N, int E) {
    __shared__ int part[512];
    const int t = threadIdx.x;
    part[t] = (t < NB) ? bhist[t] : 0;
    __syncthreads();
    for (int off = 1; off < 512; off <<= 1) {
        int v = (t >= off) ? part[t - off] : 0;
        __syncthreads();
        part[t] += v;
        __syncthreads();
    }
    int excl = (t == 0) ? 0 : part[t - 1];
    if (t < NB) { bstart[t] = excl; bcursor[t] = excl; }
    if (t == 0) { bstart[NB] = E; rs[N] = E; }
}

// multisplit scatter: LDS-sort a 4096-edge chunk by bucket, write runs contiguously
__global__ __launch_bounds__(512) void bucket_scatter(const int* __restrict__ row,
                                                      const int* __restrict__ col,
                                                      const float* __restrict__ w,
                                                      int* __restrict__ bcursor,
                                                      int2* __restrict__ brecs,
                                                      int E, int NB) {
    __shared__ int lh[512], lstart[512], lcur[512], gbase[512];
    __shared__ int   sm[SC_E];
    __shared__ float sw[SC_E];
    __shared__ short sb[SC_E];

    const int t = threadIdx.x;
    const int base = blockIdx.x * SC_E;
    const int cnt = min(SC_E, E - base);

    lh[t] = 0;
    __syncthreads();

    int   myb[8], mym[8];
    float myw[8];
#pragma unroll
    for (int k = 0; k < 8; ++k) {
        int i = t + k * 512;
        if (i < cnt) {
            int e = base + i;
            int r = row[e], c = col[e];
            myb[k] = c >> BKT_SHIFT;
            mym[k] = ((c & (BKT - 1)) << 17) | r;
            myw[k] = w[e];
            atomicAdd(&lh[myb[k]], 1);
        } else myb[k] = -1;
    }
    __syncthreads();

    int v = lh[t];
    lstart[t] = v;
    __syncthreads();
    for (int off = 1; off < 512; off <<= 1) {
        int u = (t >= off) ? lstart[t - off] : 0;
        __syncthreads();
        lstart[t] += u;
        __syncthreads();
    }
    int excl = lstart[t] - v;
    __syncthreads();
    lstart[t] = excl;
    lcur[t]   = excl;
    gbase[t]  = (t < NB) ? atomicAdd(&bcursor[t], v) : 0;
    __syncthreads();

#pragma unroll
    for (int k = 0; k < 8; ++k) {
        if (myb[k] >= 0) {
            int slot = atomicAdd(&lcur[myb[k]], 1);
            sm[slot] = mym[k];
            sw[slot] = myw[k];
            sb[slot] = (short)myb[k];
        }
    }
    __syncthreads();

    for (int j = t; j < cnt; j += 512) {
        int b = sb[j];
        int pos = gbase[b] + (j - lstart[b]);
        brecs[pos] = make_int2(sm[j], __float_as_int(sw[j]));
    }
}

// pass 1: per-node counts + weighted degree via LDS atomics -> rs, dinv
__global__ __launch_bounds__(256) void bucket_build_p1(const int2* __restrict__ brecs,
                                                       const int* __restrict__ bstart,
                                                       int* __restrict__ rs,
                                                       float* __restrict__ dinv, int N) {
    __shared__ int   lcnt[256], lscan[256];
    __shared__ float ldeg[256];
    const int b = blockIdx.x, t = threadIdx.x;
    const int s = bstart[b], e = bstart[b + 1];
    const int node0 = b << BKT_SHIFT;
    const int nNodes = min(BKT, N - node0);

    lcnt[t] = 0;
    ldeg[t] = 0.f;
    __syncthreads();

    for (int i = s + t; i < e; i += 256) {
        int2 r = brecs[i];
        int cl = r.x >> 17;
        atomicAdd(&lcnt[cl], 1);
        atomicAdd(&ldeg[cl], __int_as_float(r.y));
    }
    __syncthreads();

    int v = lcnt[t];
    lscan[t] = v;
    __syncthreads();
    for (int off = 1; off < 256; off <<= 1) {
        int u = (t >= off) ? lscan[t - off] : 0;
        __syncthreads();
        lscan[t] += u;
        __syncthreads();
    }
    if (t < nNodes) {
        rs[node0 + t] = s + (lscan[t] - v);
        float d = ldeg[t];
        dinv[node0 + t] = (d > 0.f) ? rsqrtf(d) : 0.f;
    }
}

// pass 2: node-sorted placement WITH norm computed in the same pass
// (cursor starts at rs -> global slot directly)
__global__ __launch_bounds__(256) void bucket_place(const int2* __restrict__ brecs,
                                                    const int* __restrict__ bstart,
                                                    const int* __restrict__ rs,
                                                    const float* __restrict__ dinv,
                                                    int2* __restrict__ sedge, int N) {
    __shared__ int   lcur[256];
    __shared__ float ld[256];
    const int b = blockIdx.x, t = threadIdx.x;
    const int s = bstart[b], e = bstart[b + 1];
    const int node0 = b << BKT_SHIFT;
    const int nNodes = min(BKT, N - node0);

    lcur[t] = (t < nNodes) ? rs[node0 + t] : 0;
    ld[t]   = (t < nNodes) ? dinv[node0 + t] : 0.f;
    __syncthreads();

    for (int i = s + t; i < e; i += 256) {
        int2 r = brecs[i];
        int cl   = r.x >> 17;
        int rowi = r.x & 0x1FFFF;
        float nrm = dinv[rowi] * ld[cl] * __int_as_float(r.y);
        int slot = atomicAdd(&lcur[cl], 1);
        sedge[slot] = make_int2(rowi, __float_as_int(nrm));
    }
}

// ================================================================= GEMM (bf16 MFMA)
__device__ __forceinline__ ushort f2bf(float f) {
    uint b = __float_as_uint(f);
    return (ushort)((b + 0x7FFFu + ((b >> 16) & 1u)) >> 16);  // RNE
}
__device__ __forceinline__ float bf2f(ushort u) {
    return __uint_as_float((uint)u << 16);
}
__device__ __forceinline__ uint4 pack8(const float* f) {
    uint4 o;
    o.x = f2bf(f[0]) | ((uint)f2bf(f[1]) << 16);
    o.y = f2bf(f[2]) | ((uint)f2bf(f[3]) << 16);
    o.z = f2bf(f[4]) | ((uint)f2bf(f[5]) << 16);
    o.w = f2bf(f[6]) | ((uint)f2bf(f[7]) << 16);
    return o;
}

// Persistent-W: W (and BN prologue for MODE 2) staged ONCE per block; block then
// loops over row-tiles with stride gridDim.x.
// MODE 0: X = f32, plain. MODE 2: X = bf16, BN+ReLU applied during A-staging.
template <int MODE>
__global__ __launch_bounds__(256) void gemm128_mfma(const void* __restrict__ Xv,
                                                    const float* __restrict__ W,
                                                    ushort* __restrict__ Y, int N,
                                                    const float* __restrict__ sums,
                                                    float invN) {
    __shared__ __align__(16) ushort Alds[64][128];
    __shared__ __align__(16) ushort Blds[128][128];
    __shared__ float bnmu[128], bnrs[128];

    const int t = threadIdx.x;

    if constexpr (MODE == 2) {
        if (t < 128) {
            float mu  = sums[t] * invN;
            float var = sums[128 + t] * invN - mu * mu;
            bnmu[t] = mu;
            bnrs[t] = rsqrtf(var + EPSF);
        }
    }

    for (int i = t; i < 128 * 16; i += 256) {
        int j = i >> 4, kc = (i & 15) << 3;
        float f[8];
        *(float4*)&f[0] = *(const float4*)&W[j * 128 + kc];
        *(float4*)&f[4] = *(const float4*)&W[j * 128 + kc + 4];
        *(uint4*)&Blds[j][kc ^ ((j & 7) << 3)] = pack8(f);
    }

    const int lane  = t & 63;
    const int wv    = t >> 6;
    const int arow  = wv * 16 + (lane & 15);
    const int klane = (lane >> 4) << 3;
    const int cq    = lane & 15;
    const int nTiles = (N + 63) >> 6;

    for (int tile = blockIdx.x; tile < nTiles; tile += gridDim.x) {
        const int n0 = tile * 64;
        __syncthreads();  // W/bnmu visible (1st iter); prior MFMA reads done (later)

        for (int i = t; i < 64 * 16; i += 256) {
            int r = i >> 4, kc = (i & 15) << 3;
            int n = n0 + r;
            uint4 v = make_uint4(0u, 0u, 0u, 0u);
            if (n < N) {
                if constexpr (MODE == 0) {
                    float f[8];
                    *(float4*)&f[0] = *(const float4*)&((const float*)Xv)[(size_t)n * 128 + kc];
                    *(float4*)&f[4] = *(const float4*)&((const float*)Xv)[(size_t)n * 128 + kc + 4];
                    v = pack8(f);
                } else {
                    uint4 raw = *(const uint4*)&((const ushort*)Xv)[(size_t)n * 128 + kc];
                    const uint* rw = &raw.x;
                    float f[8];
#pragma unroll
                    for (int k = 0; k < 4; ++k) {
                        float lo = __uint_as_float(rw[k] << 16);
                        float hi = __uint_as_float(rw[k] & 0xFFFF0000u);
                        f[2 * k]     = fmaxf((lo - bnmu[kc + 2 * k])     * bnrs[kc + 2 * k],     0.f);
                        f[2 * k + 1] = fmaxf((hi - bnmu[kc + 2 * k + 1]) * bnrs[kc + 2 * k + 1], 0.f);
                    }
                    v = pack8(f);
                }
            }
            *(uint4*)&Alds[r][kc ^ ((r & 7) << 3)] = v;
        }
        __syncthreads();

        f32x4 acc[8] = {};
        for (int ks = 0; ks < 4; ++ks) {
            const int k0 = ks * 32 + klane;
            bf16x8 a = *(const bf16x8*)&Alds[arow][k0 ^ ((arow & 7) << 3)];
#pragma unroll
            for (int tl = 0; tl < 8; ++tl) {
                int colr = tl * 16 + cq;
                bf16x8 bb = *(const bf16x8*)&Blds[colr][k0 ^ ((colr & 7) << 3)];
                acc[tl] = __builtin_amdgcn_mfma_f32_16x16x32_bf16(a, bb, acc[tl], 0, 0, 0);
            }
        }

        const int r0 = n0 + wv * 16 + ((lane >> 4) << 2);
#pragma unroll
        for (int tl = 0; tl < 8; ++tl) {
#pragma unroll
            for (int reg = 0; reg < 4; ++reg) {
                int rr = r0 + reg;
                if (rr < N) Y[(size_t)rr * 128 + tl * 16 + cq] = f2bf(acc[tl][reg]);
            }
        }
    }
}

// ================================================================= gather conv
// one wave per dest node. Quarter-wave grouping: quarter g (16 lanes), lane lq
// holds features [8lq..8lq+8) of edge (j+g) via ONE uint4 load -> one vmem op
// moves 4 full 256B rows; 16-edge unroll keeps 4 loads (4KB) in flight.
// All __shfl ops unconditional with in-range sources (round-9 lesson).
// Final reduce: shfl_xor(16) + shfl_xor(32) sums the 4 quarters.
__device__ __forceinline__ float bflo(uint v) { return __uint_as_float(v << 16); }
__device__ __forceinline__ float bfhi(uint v) { return __uint_as_float(v & 0xFFFF0000u); }

template <bool OUT_BF16>
__global__ __launch_bounds__(256) void agg_gather(const ushort* __restrict__ Hin,
                                                  const int2* __restrict__ sedge,
                                                  const int* __restrict__ rs,
                                                  const float* __restrict__ bias,
                                                  void* __restrict__ Hout, int N, int E) {
    int c = blockIdx.x * 4 + (threadIdx.x >> 6);
    if (c >= N) return;
    const int lane = threadIdx.x & 63;
    const int g  = lane >> 4;   // quarter id 0..3
    const int lq = lane & 15;   // lane within quarter

    float acc[8] = {0.f, 0.f, 0.f, 0.f, 0.f, 0.f, 0.f, 0.f};
    if (bias && g == 0) {
        *(float4*)&acc[0] = *(const float4*)&bias[lq * 8];
        *(float4*)&acc[4] = *(const float4*)&bias[lq * 8 + 4];
    }

    const int e0 = rs[c];
    const int deg = rs[c + 1] - e0;

    for (int base = 0; base < deg; base += 64) {
        int m = min(64, deg - base);
        int idx = e0 + base + lane;
        int2 rec = sedge[idx < E ? idx : E - 1];

        int j = 0;
#define QLOAD(p, rr, ww, vv)                                                    \
        int   rr = __shfl(rec.x, j + 4 * (p) + g);                              \
        float ww = __int_as_float(__shfl(rec.y, j + 4 * (p) + g));              \
        uint4 vv = *(const uint4*)&Hin[(size_t)rr * 128 + lq * 8];
#define QACC(ww, vv)                                                            \
        acc[0] = fmaf(ww, bflo(vv.x), acc[0]); acc[1] = fmaf(ww, bfhi(vv.x), acc[1]); \
        acc[2] = fmaf(ww, bflo(vv.y), acc[2]); acc[3] = fmaf(ww, bfhi(vv.y), acc[3]); \
        acc[4] = fmaf(ww, bflo(vv.z), acc[4]); acc[5] = fmaf(ww, bfhi(vv.z), acc[5]); \
        acc[6] = fmaf(ww, bflo(vv.w), acc[6]); acc[7] = fmaf(ww, bfhi(vv.w), acc[7]);

        for (; j + 15 < m; j += 16) {
            QLOAD(0, r0, w0, v0) QLOAD(1, r1, w1, v1)
            QLOAD(2, r2, w2, v2) QLOAD(3, r3, w3, v3)
            QACC(w0, v0) QACC(w1, v1) QACC(w2, v2) QACC(w3, v3)
        }
        for (; j < m; j += 4) {
            int jj = j + g;
            int sl = (jj < m) ? jj : j;       // always < m: source lane active
            int   r0 = __shfl(rec.x, sl);     // unconditional shfl, full exec
            float w0 = __int_as_float(__shfl(rec.y, sl));
            if (jj >= m) w0 = 0.f;            // mask AFTER the cross-lane op
            uint4 v0 = *(const uint4*)&Hin[(size_t)r0 * 128 + lq * 8];
            QACC(w0, v0)
        }
#undef QLOAD
#undef QACC
    }

#pragma unroll
    for (int k = 0; k < 8; ++k) {
        acc[k] += __shfl_xor(acc[k], 16);
        acc[k] += __shfl_xor(acc[k], 32);
    }

    if (g == 0) {
        if constexpr (OUT_BF16) {
            uint4 o;
            o.x = f2bf(acc[0]) | ((uint)f2bf(acc[1]) << 16);
            o.y = f2bf(acc[2]) | ((uint)f2bf(acc[3]) << 16);
            o.z = f2bf(acc[4]) | ((uint)f2bf(acc[5]) << 16);
            o.w = f2bf(acc[6]) | ((uint)f2bf(acc[7]) << 16);
            *(uint4*)&((uint*)Hout)[(size_t)c * 64 + lq * 4] = o;
        } else {
            *(float4*)&((float*)Hout)[(size_t)c * 128 + lq * 8]     = *(float4*)&acc[0];
            *(float4*)&((float*)Hout)[(size_t)c * 128 + lq * 8 + 4] = *(float4*)&acc[4];
        }
    }
}

// ================================================================= batchnorm stats (bf16 in)
__global__ __launch_bounds__(256) void bn_stats(const ushort* __restrict__ H,
                                                float* __restrict__ sums, int N) {
    int j = threadIdx.x & 127;
    float s = 0.f, s2 = 0.f;
    for (int n = blockIdx.x * 2 + (threadIdx.x >> 7); n < N; n += gridDim.x * 2) {
        float v = bf2f(H[(size_t)n * 128 + j]);
        s += v; s2 += v * v;
    }
    atomicAdd(&sums[j], s);
    atomicAdd(&sums[128 + j], s2);
}

// ================================================================= launch
extern "C" void kernel_launch(void* const* d_in, const int* in_sizes, int n_in,
                              void* d_out, int out_size, void* d_ws, size_t ws_size,
                              hipStream_t stream) {
    const float* x  = (const float*)d_in[0];
    const int*   ei = (const int*)d_in[1];
    const float* ew = (const float*)d_in[2];
    const float* W0 = (const float*)d_in[3];
    const float* W1 = (const float*)d_in[5];
    const float* b1 = (const float*)d_in[6];

    const int N = in_sizes[0] / 128;
    const int E = in_sizes[2];
    const int* row = ei;
    const int* col = ei + E;
    const int NB = (N + BKT - 1) >> BKT_SHIFT;  // 391 for N=100K (<=512 required)

    uintptr_t base = (uintptr_t)d_ws;
    auto alloc = [&](size_t bytes) {
        uintptr_t p = base;
        base += (bytes + 255) & ~(size_t)255;
        return (void*)p;
    };
    float*  dinv   = (float*) alloc((size_t)N * 4);
    float*  sums   = (float*) alloc(256 * 4);
    int*    bhist  = (int*)   alloc((size_t)(NB + 1) * 4);
    int*    bstart = (int*)   alloc((size_t)(NB + 1) * 4);
    int*    bcursor= (int*)   alloc((size_t)NB * 4);
    int*    rs     = (int*)   alloc((size_t)(N + 1) * 4);
    int2*   sedge  = (int2*)  alloc((size_t)E * 8);        // final {row, norm}
    ushort* hA     = (ushort*)alloc((size_t)N * 128 * 2);  // bf16 feature buffers
    ushort* hB     = (ushort*)alloc((size_t)N * 128 * 2);
    // brecs (bucket-partitioned temps) aliases hB: hB first written by conv1,
    // long after bucket_place consumed brecs.
    int2*   brecs  = (int2*)hB;
    float*  out    = (float*) d_out;
    (void)ws_size; (void)n_in; (void)out_size;

    const float invN = 1.f / (float)N;

    // per-call zeroing (harness does not re-poison between replays)
    hipMemsetAsync(bhist, 0, (size_t)(NB + 1) * 4, stream);
    hipMemsetAsync(sums, 0, 256 * 4, stream);

    // --- CSR build
    bucket_hist<<<1024, 512, 0, stream>>>(col, bhist, E, NB);
    scan_buckets<<<1, 512, 0, stream>>>(bhist, bstart, bcursor, rs, NB, N, E);
    bucket_scatter<<<(E + SC_E - 1) / SC_E, 512, 0, stream>>>(row, col, ew, bcursor,
                                                              brecs, E, NB);
    bucket_build_p1<<<NB, 256, 0, stream>>>(brecs, bstart, rs, dinv, N);
    bucket_place<<<NB, 256, 0, stream>>>(brecs, bstart, rs, dinv, sedge, N);

    const int nTiles = (N + 63) / 64;
    const int gemmGrid = nTiles < 512 ? nTiles : 512;

    // --- layer 0: hA(bf16) = x @ W0^T
    gemm128_mfma<0><<<gemmGrid, 256, 0, stream>>>(x, W0, hA, N, nullptr, 0.f);

    // --- conv 1: hB(bf16) = gather-reduce(hA)
    agg_gather<true><<<(N + 3) / 4, 256, 0, stream>>>(hA, sedge, rs, nullptr, hB, N, E);

    // --- BN stats on bf16 conv output (b0 cancels inside BN)
    bn_stats<<<512, 256, 0, stream>>>(hB, sums, N);

    // --- layer 1 (BN+ReLU fused into A-staging): hA(bf16) = relu(BN(hB)) @ W1^T
    gemm128_mfma<2><<<gemmGrid, 256, 0, stream>>>(hB, W1, hA, N, sums, invN);

    // --- conv 2 (+ b1): out(f32) = gather-reduce(hA) + b1
    agg_gather<false><<<(N + 3) / 4, 256, 0, stream>>>(hA, sedge, rs, b1, out, N, E);
}